// Round 1
// baseline (101.441 us; speedup 1.0000x reference)
//
#include <hip/hip_runtime.h>

#define OT 32          // output tile edge
#define IT 40          // input tile edge = OT + 8 (two 5x5 valid convs => halo 8)
#define DT 36          // deviation/product tile edge = OT + 4
#define H 1024
#define W 1024
#define OH 1016
#define OW 1016
#define NB 16

__global__ __launch_bounds__(256)
void cov_kernel(const float* __restrict__ x,
                const float* __restrict__ y,
                float* __restrict__ out) {
    __shared__ float sx[IT][IT + 1];
    __shared__ float sy[IT][IT + 1];
    __shared__ float cx[DT][IT + 1];
    __shared__ float cy[DT][IT + 1];
    __shared__ float prod[DT][DT + 1];
    __shared__ float cp[OT][DT + 1];

    const int b  = blockIdx.z;
    const int i0 = blockIdx.y * OT;
    const int j0 = blockIdx.x * OT;
    const int tid = threadIdx.x;

    const float* xb = x + (size_t)b * H * W;
    const float* yb = y + (size_t)b * H * W;

    // 1) global -> LDS (40x40 tile, zero-pad out-of-range; those never feed a
    //    valid output since valid outputs only need rows/cols <= 1023)
    for (int idx = tid; idx < IT * IT; idx += 256) {
        int r = idx / IT, c = idx % IT;
        int gr = i0 + r, gc = j0 + c;
        float vx = 0.f, vy = 0.f;
        if (gr < H && gc < W) {
            vx = xb[gr * W + gc];
            vy = yb[gr * W + gc];
        }
        sx[r][c] = vx;
        sy[r][c] = vy;
    }
    __syncthreads();

    // 2) vertical 5-sum of inputs: cx[r][c] = sum_{u=0..4} sx[r+u][c]
    for (int idx = tid; idx < DT * IT; idx += 256) {
        int r = idx / IT, c = idx % IT;
        float ax = 0.f, ay = 0.f;
        #pragma unroll
        for (int u = 0; u < 5; ++u) { ax += sx[r + u][c]; ay += sy[r + u][c]; }
        cx[r][c] = ax;
        cy[r][c] = ay;
    }
    __syncthreads();

    // 3) horizontal 5-sum -> 5x5 mean; deviation; product
    const float inv25 = 1.0f / 25.0f;
    for (int idx = tid; idx < DT * DT; idx += 256) {
        int r = idx / DT, c = idx % DT;
        float mx = 0.f, my = 0.f;
        #pragma unroll
        for (int v = 0; v < 5; ++v) { mx += cx[r][c + v]; my += cy[r][c + v]; }
        float dx = sx[r + 2][c + 2] - mx * inv25;
        float dy = sy[r + 2][c + 2] - my * inv25;
        prod[r][c] = dx * dy;
    }
    __syncthreads();

    // 4) vertical 5-sum of product
    for (int idx = tid; idx < OT * DT; idx += 256) {
        int r = idx / DT, c = idx % DT;
        float a = 0.f;
        #pragma unroll
        for (int u = 0; u < 5; ++u) a += prod[r + u][c];
        cp[r][c] = a;
    }
    __syncthreads();

    // 5) horizontal 5-sum -> final mean; store
    for (int idx = tid; idx < OT * OT; idx += 256) {
        int r = idx / OT, c = idx % OT;
        int gi = i0 + r, gj = j0 + c;
        if (gi < OH && gj < OW) {
            float a = 0.f;
            #pragma unroll
            for (int v = 0; v < 5; ++v) a += cp[r][c + v];
            out[(size_t)b * OH * OW + (size_t)gi * OW + gj] = a * inv25;
        }
    }
}

extern "C" void kernel_launch(void* const* d_in, const int* in_sizes, int n_in,
                              void* d_out, int out_size, void* d_ws, size_t ws_size,
                              hipStream_t stream) {
    const float* x = (const float*)d_in[0];
    const float* y = (const float*)d_in[1];
    // d_in[2] is the constant 1/25 mean mask; folded into inv25.
    float* out = (float*)d_out;

    dim3 grid((OW + OT - 1) / OT, (OH + OT - 1) / OT, NB);
    dim3 block(256);
    cov_kernel<<<grid, block, 0, stream>>>(x, y, out);
}

// Round 2
// 70.702 us; speedup vs baseline: 1.4348x; 1.4348x over previous
//
#include <hip/hip_runtime.h>

#define H 1024
#define W 1024
#define OH 1016
#define OW 1016
#define NB 16

#define OTW 64         // output tile cols
#define OTH 32         // output tile rows
#define ITW 72         // input tile cols  (OTW + 8)
#define ITH 40         // input tile rows  (OTH + 8)
#define DTW 68         // dev/prod tile cols (OTW + 4)
#define DTH 36         // dev/prod tile rows (OTH + 4)

#define W4I 18         // ITW/4 float4 per input row
#define W4D 17         // DTW/4 float4 per dev row
#define W4O 16         // OTW/4 float4 per out row
#define S4  19         // padded row stride in float4 (+1 to stagger banks)

__global__ __launch_bounds__(256)
void cov_kernel(const float* __restrict__ x,
                const float* __restrict__ y,
                float* __restrict__ out) {
    __shared__ float4 sx4[ITH][S4];   // input x tile; reused as cp4 in phase 4/5
    __shared__ float4 sy4[ITH][S4];   // input y tile
    __shared__ float4 cx4[DTH][S4];   // vertical 5-sums of x
    __shared__ float4 cy4[DTH][S4];   // vertical 5-sums of y
    __shared__ float4 pr4[DTH][S4];   // dev-product tile

    const int b  = blockIdx.z;
    const int i0 = blockIdx.y * OTH;
    const int j0 = blockIdx.x * OTW;
    const int tid = threadIdx.x;
    const float inv25 = 1.0f / 25.0f;

    const float* xb = x + (size_t)b * H * W;
    const float* yb = y + (size_t)b * H * W;

    // ---- Phase 1: global -> LDS, float4 ----
    for (int idx = tid; idx < ITH * W4I; idx += 256) {
        int r  = idx / W4I;
        int c4 = idx - r * W4I;
        int gr = i0 + r;
        int gc = j0 + c4 * 4;
        float4 vx = make_float4(0.f, 0.f, 0.f, 0.f);
        float4 vy = vx;
        if (gr < H && gc <= W - 4) {           // float4 fully in range or fully out
            vx = *reinterpret_cast<const float4*>(xb + gr * W + gc);
            vy = *reinterpret_cast<const float4*>(yb + gr * W + gc);
        }
        sx4[r][c4] = vx;
        sy4[r][c4] = vy;
    }
    __syncthreads();

    // ---- Phase 2: vertical 5-sum of inputs ----
    for (int idx = tid; idx < DTH * W4I; idx += 256) {
        int r  = idx / W4I;
        int c4 = idx - r * W4I;
        float4 ax = sx4[r][c4];
        float4 ay = sy4[r][c4];
        #pragma unroll
        for (int u = 1; u < 5; ++u) {
            float4 tx = sx4[r + u][c4];
            float4 ty = sy4[r + u][c4];
            ax.x += tx.x; ax.y += tx.y; ax.z += tx.z; ax.w += tx.w;
            ay.x += ty.x; ay.y += ty.y; ay.z += ty.z; ay.w += ty.w;
        }
        cx4[r][c4] = ax;
        cy4[r][c4] = ay;
    }
    __syncthreads();

    // ---- Phase 3: horizontal 5-sum -> mean; deviation; product ----
    for (int idx = tid; idx < DTH * W4D; idx += 256) {
        int r  = idx / W4D;
        int c4 = idx - r * W4D;
        float4 a = cx4[r][c4], bb = cx4[r][c4 + 1];
        float sx0 = a.x + a.y + a.z + a.w + bb.x;
        float sx1 = sx0 - a.x + bb.y;
        float sx2 = sx1 - a.y + bb.z;
        float sx3 = sx2 - a.z + bb.w;
        float4 c = cy4[r][c4], d = cy4[r][c4 + 1];
        float sy0 = c.x + c.y + c.z + c.w + d.x;
        float sy1 = sy0 - c.x + d.y;
        float sy2 = sy1 - c.y + d.z;
        float sy3 = sy2 - c.z + d.w;
        // centers: x[r+2][4*c4+2 .. 4*c4+5]
        float4 xc0 = sx4[r + 2][c4], xc1 = sx4[r + 2][c4 + 1];
        float4 yc0 = sy4[r + 2][c4], yc1 = sy4[r + 2][c4 + 1];
        float4 p;
        p.x = (xc0.z - sx0 * inv25) * (yc0.z - sy0 * inv25);
        p.y = (xc0.w - sx1 * inv25) * (yc0.w - sy1 * inv25);
        p.z = (xc1.x - sx2 * inv25) * (yc1.x - sy2 * inv25);
        p.w = (xc1.y - sx3 * inv25) * (yc1.y - sy3 * inv25);
        pr4[r][c4] = p;
    }
    __syncthreads();

    // ---- Phase 4: vertical 5-sum of product (cp aliases dead sx4) ----
    float4 (*cp4)[S4] = sx4;
    for (int idx = tid; idx < OTH * W4D; idx += 256) {
        int r  = idx / W4D;
        int c4 = idx - r * W4D;
        float4 a = pr4[r][c4];
        #pragma unroll
        for (int u = 1; u < 5; ++u) {
            float4 t = pr4[r + u][c4];
            a.x += t.x; a.y += t.y; a.z += t.z; a.w += t.w;
        }
        cp4[r][c4] = a;
    }
    __syncthreads();

    // ---- Phase 5: horizontal 5-sum -> final mean; float4 store ----
    for (int idx = tid; idx < OTH * W4O; idx += 256) {
        int r  = idx / W4O;
        int c4 = idx - r * W4O;
        int gi = i0 + r;
        int gj = j0 + c4 * 4;
        if (gi < OH && gj <= OW - 4) {
            float4 a = cp4[r][c4], bb = cp4[r][c4 + 1];
            float s0 = a.x + a.y + a.z + a.w + bb.x;
            float s1 = s0 - a.x + bb.y;
            float s2 = s1 - a.y + bb.z;
            float s3 = s2 - a.z + bb.w;
            float4 o;
            o.x = s0 * inv25; o.y = s1 * inv25; o.z = s2 * inv25; o.w = s3 * inv25;
            *reinterpret_cast<float4*>(out + (size_t)b * OH * OW + (size_t)gi * OW + gj) = o;
        }
    }
}

extern "C" void kernel_launch(void* const* d_in, const int* in_sizes, int n_in,
                              void* d_out, int out_size, void* d_ws, size_t ws_size,
                              hipStream_t stream) {
    const float* x = (const float*)d_in[0];
    const float* y = (const float*)d_in[1];
    float* out = (float*)d_out;

    dim3 grid((OW + OTW - 1) / OTW, (OH + OTH - 1) / OTH, NB);
    dim3 block(256);
    cov_kernel<<<grid, block, 0, stream>>>(x, y, out);
}